// Round 1
// baseline (744.982 us; speedup 1.0000x reference)
//
#include <hip/hip_runtime.h>
#include <float.h>
#include <math.h>

#define N_PTS   8192
#define NCHUNK  8
#define CHUNK   (N_PTS / NCHUNK)   // 1024
#define QBLK    256
#define QBLOCKS (N_PTS / QBLK)     // 32
#define STEPS   11                 // STEPLIM + 1
#define TOLV    1e-4

struct IcpState {
    double err;
    int    done;
    int    pad;
    double R[3][3];
    double t[3];
};

// ---- ws layout (bytes) ----
// temppc : 0       float  [N*3]      =  98304
// p2f    : 98304   float4 [N]        = 131072  (end 229376)
// pd2    : 229376  float  [NCHUNK*N] = 262144  (end 491520)
// pidx   : 491520  int    [NCHUNK*N] = 262144  (end 753664)
// bpart  : 753664  double [QBLOCKS*16] = 4096  (end 757760)
// state  : 757760  IcpState
#define WS_TEMPPC 0
#define WS_P2F    98304
#define WS_PD2    229376
#define WS_PIDX   491520
#define WS_BPART  753664
#define WS_STATE  757760

// ---------------------------------------------------------------------------
__global__ void icp_init(const float* __restrict__ p1, const float* __restrict__ p2,
                         float* __restrict__ temppc, float4* __restrict__ p2f,
                         IcpState* st) {
    int i = blockIdx.x * blockDim.x + threadIdx.x;
    if (i < N_PTS) {
        float x = p2[3*i], y = p2[3*i+1], z = p2[3*i+2];
        p2f[i] = make_float4(x, y, z, x*x + y*y + z*z);
        temppc[3*i]   = p1[3*i];
        temppc[3*i+1] = p1[3*i+1];
        temppc[3*i+2] = p1[3*i+2];
    }
    if (i == 0) {
        st->err  = __builtin_inf();
        st->done = 0;
    }
}

// ---------------------------------------------------------------------------
// Partial 1-NN: each block = (query block qb, candidate chunk cc).
// Stores per-(query,chunk) best of (|s|^2 - 2 q.s) and its index.
__global__ void nn_partial(const float* __restrict__ temppc, const float4* __restrict__ p2f,
                           float* __restrict__ pd2, int* __restrict__ pidx) {
    __shared__ float4 s[CHUNK];  // 16 KB
    int qb  = blockIdx.x;
    int cc  = blockIdx.y;
    int tid = threadIdx.x;
    int cbase = cc * CHUNK;
    for (int j = tid; j < CHUNK; j += QBLK) s[j] = p2f[cbase + j];
    __syncthreads();

    int q = qb * QBLK + tid;
    float qx = temppc[3*q], qy = temppc[3*q+1], qz = temppc[3*q+2];
    float best = FLT_MAX;
    int   bidx = cbase;
    #pragma unroll 8
    for (int j = 0; j < CHUNK; ++j) {
        float4 sj = s[j];
        float dot = qx*sj.x + qy*sj.y + qz*sj.z;
        float val = sj.w - 2.0f*dot;     // |s|^2 - 2 q.s  (|q|^2 added later)
        bool lt = val < best;
        best = lt ? val : best;
        bidx = lt ? (cbase + j) : bidx;
    }
    pd2 [cc * N_PTS + q] = best;
    pidx[cc * N_PTS + q] = bidx;
}

// ---------------------------------------------------------------------------
// Deterministic 256-thread block reduce of 16 doubles; thread 0 stores to dst[16].
__device__ __forceinline__ void block_reduce16_store(double vals[16], double* dst) {
    #pragma unroll
    for (int k = 0; k < 16; ++k) {
        double v = vals[k];
        #pragma unroll
        for (int off = 32; off > 0; off >>= 1) v += __shfl_down(v, off, 64);
        vals[k] = v;
    }
    __shared__ double sred[4][16];
    int wave = threadIdx.x >> 6;
    int lane = threadIdx.x & 63;
    if (lane == 0) {
        #pragma unroll
        for (int k = 0; k < 16; ++k) sred[wave][k] = vals[k];
    }
    __syncthreads();
    if (threadIdx.x == 0) {
        #pragma unroll
        for (int k = 0; k < 16; ++k)
            dst[k] = sred[0][k] + sred[1][k] + sred[2][k] + sred[3][k];
    }
}

// ---------------------------------------------------------------------------
// Combine chunk partials -> final NN; fuse gather + sums for centroids/covariance.
// vals: [0]=dmin, [1..3]=a, [4..6]=b, [7..15]=a_i*b_j
__global__ void nn_combine(const float* __restrict__ temppc, const float4* __restrict__ p2f,
                           const float* __restrict__ pd2, const int* __restrict__ pidx,
                           double* __restrict__ bpart) {
    int q = blockIdx.x * blockDim.x + threadIdx.x;
    float best = pd2[q];
    int   bidx = pidx[q];
    #pragma unroll
    for (int c = 1; c < NCHUNK; ++c) {
        float v = pd2[c * N_PTS + q];
        if (v < best) { best = v; bidx = pidx[c * N_PTS + q]; }
    }
    float ax = temppc[3*q], ay = temppc[3*q+1], az = temppc[3*q+2];
    float q2 = ax*ax + ay*ay + az*az;
    float d2 = fmaxf(best + q2, 0.0f);
    float dmin = sqrtf(d2);
    float4 b = p2f[bidx];

    double vals[16];
    vals[0] = (double)dmin;
    vals[1] = (double)ax;  vals[2] = (double)ay;  vals[3] = (double)az;
    vals[4] = (double)b.x; vals[5] = (double)b.y; vals[6] = (double)b.z;
    vals[7]  = (double)ax * b.x; vals[8]  = (double)ax * b.y; vals[9]  = (double)ax * b.z;
    vals[10] = (double)ay * b.x; vals[11] = (double)ay * b.y; vals[12] = (double)ay * b.z;
    vals[13] = (double)az * b.x; vals[14] = (double)az * b.y; vals[15] = (double)az * b.z;
    block_reduce16_store(vals, bpart + blockIdx.x * 16);
}

// ---------------------------------------------------------------------------
// Partial sums for the final fit (a = p1, b = temppc), slot 0 unused.
__global__ void fit_partial(const float* __restrict__ a, const float* __restrict__ b,
                            double* __restrict__ bpart) {
    int q = blockIdx.x * blockDim.x + threadIdx.x;
    float ax = a[3*q], ay = a[3*q+1], az = a[3*q+2];
    float bx = b[3*q], by = b[3*q+1], bz = b[3*q+2];
    double vals[16];
    vals[0] = 0.0;
    vals[1] = (double)ax;  vals[2] = (double)ay;  vals[3] = (double)az;
    vals[4] = (double)bx;  vals[5] = (double)by;  vals[6] = (double)bz;
    vals[7]  = (double)ax * bx; vals[8]  = (double)ax * by; vals[9]  = (double)ax * bz;
    vals[10] = (double)ay * bx; vals[11] = (double)ay * by; vals[12] = (double)ay * bz;
    vals[13] = (double)az * bx; vals[14] = (double)az * by; vals[15] = (double)az * bz;
    block_reduce16_store(vals, bpart + blockIdx.x * 16);
}

// ---------------------------------------------------------------------------
// Kabsch via Jacobi eigendecomposition of H^T H (all double, single thread).
__device__ void kabsch3(const double H[3][3], const double c1[3], const double c2[3],
                        double R[3][3], double t[3]) {
    double A[3][3];
    for (int i = 0; i < 3; ++i)
        for (int j = 0; j < 3; ++j) {
            double sacc = 0.0;
            for (int k = 0; k < 3; ++k) sacc += H[k][i] * H[k][j];
            A[i][j] = sacc;
        }
    double V[3][3] = {{1,0,0},{0,1,0},{0,0,1}};
    for (int sweep = 0; sweep < 20; ++sweep) {
        const int PQ[3][2] = {{0,1},{0,2},{1,2}};
        for (int m = 0; m < 3; ++m) {
            int p = PQ[m][0], q = PQ[m][1];
            double apq = A[p][q];
            if (fabs(apq) < 1e-300) continue;
            double app = A[p][p], aqq = A[q][q];
            double tau = (aqq - app) / (2.0 * apq);
            double tt = (tau >= 0.0) ? 1.0 / (tau + sqrt(1.0 + tau*tau))
                                     : 1.0 / (tau - sqrt(1.0 + tau*tau));
            double c = 1.0 / sqrt(1.0 + tt*tt), s = tt * c;
            A[p][p] = app - tt * apq;
            A[q][q] = aqq + tt * apq;
            A[p][q] = 0.0; A[q][p] = 0.0;
            int k = 3 - p - q;
            double akp = A[k][p], akq = A[k][q];
            A[k][p] = c*akp - s*akq; A[p][k] = A[k][p];
            A[k][q] = s*akp + c*akq; A[q][k] = A[k][q];
            for (int r = 0; r < 3; ++r) {
                double vp = V[r][p], vq = V[r][q];
                V[r][p] = c*vp - s*vq;
                V[r][q] = s*vp + c*vq;
            }
        }
    }
    double lam[3] = {A[0][0], A[1][1], A[2][2]};
    int ord[3] = {0,1,2};
    for (int i = 0; i < 2; ++i)
        for (int j = i+1; j < 3; ++j)
            if (lam[ord[j]] > lam[ord[i]]) { int tmp = ord[i]; ord[i] = ord[j]; ord[j] = tmp; }
    double v0[3] = {V[0][ord[0]], V[1][ord[0]], V[2][ord[0]]};
    double v1[3] = {V[0][ord[1]], V[1][ord[1]], V[2][ord[1]]};
    double v2[3] = {V[0][ord[2]], V[1][ord[2]], V[2][ord[2]]};

    double u0[3], u1[3], hv2[3];
    for (int i = 0; i < 3; ++i) u0[i] = H[i][0]*v0[0] + H[i][1]*v0[1] + H[i][2]*v0[2];
    double n0 = sqrt(u0[0]*u0[0] + u0[1]*u0[1] + u0[2]*u0[2]);
    n0 = fmax(n0, 1e-300);
    for (int i = 0; i < 3; ++i) u0[i] /= n0;

    for (int i = 0; i < 3; ++i) u1[i] = H[i][0]*v1[0] + H[i][1]*v1[1] + H[i][2]*v1[2];
    double d01 = u1[0]*u0[0] + u1[1]*u0[1] + u1[2]*u0[2];
    for (int i = 0; i < 3; ++i) u1[i] -= d01 * u0[i];
    double n1 = sqrt(u1[0]*u1[0] + u1[1]*u1[1] + u1[2]*u1[2]);
    n1 = fmax(n1, 1e-300);
    for (int i = 0; i < 3; ++i) u1[i] /= n1;

    double u2[3] = {u0[1]*u1[2] - u0[2]*u1[1],
                    u0[2]*u1[0] - u0[0]*u1[2],
                    u0[0]*u1[1] - u0[1]*u1[0]};
    for (int i = 0; i < 3; ++i) hv2[i] = H[i][0]*v2[0] + H[i][1]*v2[1] + H[i][2]*v2[2];
    if (hv2[0]*u2[0] + hv2[1]*u2[1] + hv2[2]*u2[2] < 0.0) {
        v2[0] = -v2[0]; v2[1] = -v2[1]; v2[2] = -v2[2];
    }
    // det(V) with columns v0,v1,v2 ; det(U) = +1 by construction
    double cx = v1[1]*v2[2] - v1[2]*v2[1];
    double cy = v1[2]*v2[0] - v1[0]*v2[2];
    double cz = v1[0]*v2[1] - v1[1]*v2[0];
    double detV = v0[0]*cx + v0[1]*cy + v0[2]*cz;
    double dsg = (detV < 0.0) ? -1.0 : 1.0;

    for (int i = 0; i < 3; ++i)
        for (int j = 0; j < 3; ++j)
            R[i][j] = v0[i]*u0[j] + v1[i]*u1[j] + dsg * v2[i]*u2[j];
    for (int i = 0; i < 3; ++i)
        t[i] = c2[i] - (R[i][0]*c1[0] + R[i][1]*c1[1] + R[i][2]*c1[2]);
}

// ---------------------------------------------------------------------------
__global__ void icp_update(const double* __restrict__ bpart, IcpState* st) {
    if (threadIdx.x != 0 || blockIdx.x != 0) return;
    double s[16];
    for (int k = 0; k < 16; ++k) s[k] = 0.0;
    for (int b = 0; b < QBLOCKS; ++b)
        for (int k = 0; k < 16; ++k) s[k] += bpart[b*16 + k];
    const double Nn = (double)N_PTS;
    double errnew = s[0] / Nn;
    double c1[3] = {s[1]/Nn, s[2]/Nn, s[3]/Nn};
    double c2[3] = {s[4]/Nn, s[5]/Nn, s[6]/Nn};
    double H[3][3];
    for (int i = 0; i < 3; ++i)
        for (int j = 0; j < 3; ++j)
            H[i][j] = s[7 + 3*i + j] - Nn * c1[i] * c2[j];
    double err = st->err;
    int done = st->done;
    double rel = fabs((errnew - err) / err);     // nan on first iter -> cond false
    int cond = (rel < TOLV) ? 1 : 0;
    int nd = done | cond;
    if (!nd) {
        double R[3][3], t[3];
        kabsch3(H, c1, c2, R, t);
        for (int i = 0; i < 3; ++i)
            for (int j = 0; j < 3; ++j) st->R[i][j] = R[i][j];
        st->t[0] = t[0]; st->t[1] = t[1]; st->t[2] = t[2];
        st->err = errnew;
    }
    st->done = nd;
}

// ---------------------------------------------------------------------------
__global__ void icp_transform(float* __restrict__ temppc, const IcpState* __restrict__ st) {
    if (st->done) return;
    int i = blockIdx.x * blockDim.x + threadIdx.x;
    double x = temppc[3*i], y = temppc[3*i+1], z = temppc[3*i+2];
    double nx = st->R[0][0]*x + st->R[0][1]*y + st->R[0][2]*z + st->t[0];
    double ny = st->R[1][0]*x + st->R[1][1]*y + st->R[1][2]*z + st->t[1];
    double nz = st->R[2][0]*x + st->R[2][1]*y + st->R[2][2]*z + st->t[2];
    temppc[3*i]   = (float)nx;
    temppc[3*i+1] = (float)ny;
    temppc[3*i+2] = (float)nz;
}

// ---------------------------------------------------------------------------
__global__ void final_svd(const double* __restrict__ bpart, float* __restrict__ out) {
    if (threadIdx.x != 0 || blockIdx.x != 0) return;
    double s[16];
    for (int k = 0; k < 16; ++k) s[k] = 0.0;
    for (int b = 0; b < QBLOCKS; ++b)
        for (int k = 0; k < 16; ++k) s[k] += bpart[b*16 + k];
    const double Nn = (double)N_PTS;
    double c1[3] = {s[1]/Nn, s[2]/Nn, s[3]/Nn};
    double c2[3] = {s[4]/Nn, s[5]/Nn, s[6]/Nn};
    double H[3][3];
    for (int i = 0; i < 3; ++i)
        for (int j = 0; j < 3; ++j)
            H[i][j] = s[7 + 3*i + j] - Nn * c1[i] * c2[j];
    double R[3][3], t[3];
    kabsch3(H, c1, c2, R, t);
    for (int i = 0; i < 3; ++i) {
        out[4*i + 0] = (float)R[i][0];
        out[4*i + 1] = (float)R[i][1];
        out[4*i + 2] = (float)R[i][2];
        out[4*i + 3] = (float)t[i];
    }
}

// ---------------------------------------------------------------------------
extern "C" void kernel_launch(void* const* d_in, const int* in_sizes, int n_in,
                              void* d_out, int out_size, void* d_ws, size_t ws_size,
                              hipStream_t stream) {
    const float* p1 = (const float*)d_in[0];
    const float* p2 = (const float*)d_in[1];
    float* out = (float*)d_out;
    char* ws = (char*)d_ws;

    float*    temppc = (float*)   (ws + WS_TEMPPC);
    float4*   p2f    = (float4*)  (ws + WS_P2F);
    float*    pd2    = (float*)   (ws + WS_PD2);
    int*      pidx   = (int*)     (ws + WS_PIDX);
    double*   bpart  = (double*)  (ws + WS_BPART);
    IcpState* st     = (IcpState*)(ws + WS_STATE);

    icp_init<<<QBLOCKS, QBLK, 0, stream>>>(p1, p2, temppc, p2f, st);
    for (int it = 0; it < STEPS; ++it) {
        nn_partial<<<dim3(QBLOCKS, NCHUNK), QBLK, 0, stream>>>(temppc, p2f, pd2, pidx);
        nn_combine<<<QBLOCKS, QBLK, 0, stream>>>(temppc, p2f, pd2, pidx, bpart);
        icp_update<<<1, 64, 0, stream>>>(bpart, st);
        icp_transform<<<QBLOCKS, QBLK, 0, stream>>>(temppc, st);
    }
    fit_partial<<<QBLOCKS, QBLK, 0, stream>>>(p1, temppc, bpart);
    final_svd<<<1, 64, 0, stream>>>(bpart, out);
}

// Round 2
// 582.319 us; speedup vs baseline: 1.2793x; 1.2793x over previous
//
#include <hip/hip_runtime.h>
#include <float.h>
#include <math.h>

#define N_PTS   8192
#define NCH     64          // candidate chunks
#define CH      128         // candidates per chunk (N/NCH)
#define STEPS   11          // STEPLIM + 1
#define TOLV    1e-4
#define BPGRID  128         // combine/fit grid (64 threads each -> 8192 queries)

// ---- ws layout (bytes) ----
#define WS_TEMPPC 0         // float [N*3]        =   98304
#define WS_P2F    98304     // float4[N]          =  131072 -> 229376
#define WS_PIDX   229376    // ushort[NCH*N]      = 1048576 -> 1277952
#define WS_BPART  1277952   // double[BPGRID*16]  =   16384 -> 1294336
#define WS_ERRH   1294336   // double[16]         ->  1294464
#define WS_DONEH  1294464   // int[16]            ->  1294528

// ---------------------------------------------------------------------------
__global__ void icp_init(const float* __restrict__ p1, const float* __restrict__ p2,
                         float* __restrict__ temppc, float4* __restrict__ p2f,
                         double* __restrict__ err_hist, int* __restrict__ done_hist) {
    int i = blockIdx.x * blockDim.x + threadIdx.x;
    if (i < N_PTS) {
        float x = p2[3*i], y = p2[3*i+1], z = p2[3*i+2];
        p2f[i] = make_float4(x, y, z, x*x + y*y + z*z);
        temppc[3*i]   = p1[3*i];
        temppc[3*i+1] = p1[3*i+1];
        temppc[3*i+2] = p1[3*i+2];
    }
    if (i == 0) {
        err_hist[0]  = __builtin_inf();
        done_hist[0] = 0;
    }
}

// ---------------------------------------------------------------------------
// Partial 1-NN. Each block = (query block qb: 1024 queries, chunk cc: 128 cands).
// QPT=4 queries/thread; explicit 4-deep LDS prefetch. Stores winner index only.
__global__ void nn_partial(const float* __restrict__ temppc, const float4* __restrict__ p2f,
                           unsigned short* __restrict__ pidx,
                           const int* __restrict__ done_hist, int it) {
    if (done_hist[it]) return;
    __shared__ float4 s[CH];   // 2 KB
    int qb  = blockIdx.x;
    int cc  = blockIdx.y;
    int tid = threadIdx.x;
    int cbase = cc * CH;
    if (tid < CH) s[tid] = p2f[cbase + tid];
    __syncthreads();

    int q0 = qb * 1024 + tid;          // queries q0 + 256*k
    float m2x[4], m2y[4], m2z[4];
    float best[4];
    int   bj[4];
    #pragma unroll
    for (int k = 0; k < 4; ++k) {
        int q = q0 + 256*k;
        m2x[k] = -2.0f * temppc[3*q];
        m2y[k] = -2.0f * temppc[3*q+1];
        m2z[k] = -2.0f * temppc[3*q+2];
        best[k] = FLT_MAX;
        bj[k] = 0;
    }

#define PROC(SJ, JJ)                                            \
    {                                                           \
        _Pragma("unroll")                                       \
        for (int k = 0; k < 4; ++k) {                           \
            float val = fmaf(m2x[k], (SJ).x, (SJ).w);           \
            val = fmaf(m2y[k], (SJ).y, val);                    \
            val = fmaf(m2z[k], (SJ).z, val);                    \
            if (val < best[k]) { best[k] = val; bj[k] = (JJ); } \
        }                                                       \
    }

    float4 c0 = s[0], c1 = s[1], c2 = s[2], c3 = s[3];
    int j = 0;
    #pragma unroll 4
    for (; j < CH - 4; j += 4) {
        float4 n0 = s[j+4], n1 = s[j+5], n2 = s[j+6], n3 = s[j+7];
        PROC(c0, j); PROC(c1, j+1); PROC(c2, j+2); PROC(c3, j+3);
        c0 = n0; c1 = n1; c2 = n2; c3 = n3;
    }
    PROC(c0, j); PROC(c1, j+1); PROC(c2, j+2); PROC(c3, j+3);
#undef PROC

    #pragma unroll
    for (int k = 0; k < 4; ++k)
        pidx[cc * N_PTS + q0 + 256*k] = (unsigned short)(cbase + bj[k]);
}

// ---------------------------------------------------------------------------
// Wave-level (64-thread-block) deterministic reduce of 16 doubles.
__device__ __forceinline__ void wave_reduce16_store(double vals[16], double* dst) {
    int lane = threadIdx.x & 63;
    #pragma unroll
    for (int k = 0; k < 16; ++k) {
        double v = vals[k];
        #pragma unroll
        for (int off = 32; off > 0; off >>= 1) v += __shfl_down(v, off, 64);
        if (lane == 0) dst[k] = v;
    }
}

// ---------------------------------------------------------------------------
// Combine chunk winners -> final NN; fuse gather + centroid/covariance sums.
// grid BPGRID x 64 threads, 1 query/thread.
__global__ void nn_combine(const float* __restrict__ temppc, const float4* __restrict__ p2f,
                           const unsigned short* __restrict__ pidx,
                           double* __restrict__ bpart,
                           const int* __restrict__ done_hist, int it) {
    if (done_hist[it]) return;
    int q = blockIdx.x * 64 + threadIdx.x;
    float ax = temppc[3*q], ay = temppc[3*q+1], az = temppc[3*q+2];
    float m2x = -2.0f*ax, m2y = -2.0f*ay, m2z = -2.0f*az;
    float best = FLT_MAX;
    int   bi = 0;
    #pragma unroll 8
    for (int c = 0; c < NCH; ++c) {
        int idx = pidx[c * N_PTS + q];
        float4 sj = p2f[idx];
        float val = fmaf(m2x, sj.x, sj.w);
        val = fmaf(m2y, sj.y, val);
        val = fmaf(m2z, sj.z, val);
        if (val < best) { best = val; bi = idx; }
    }
    float q2 = ax*ax + ay*ay + az*az;
    float d2 = fmaxf(best + q2, 0.0f);
    float dmin = sqrtf(d2);
    float4 b = p2f[bi];

    double vals[16];
    vals[0] = (double)dmin;
    vals[1] = (double)ax;  vals[2] = (double)ay;  vals[3] = (double)az;
    vals[4] = (double)b.x; vals[5] = (double)b.y; vals[6] = (double)b.z;
    vals[7]  = (double)ax * b.x; vals[8]  = (double)ax * b.y; vals[9]  = (double)ax * b.z;
    vals[10] = (double)ay * b.x; vals[11] = (double)ay * b.y; vals[12] = (double)ay * b.z;
    vals[13] = (double)az * b.x; vals[14] = (double)az * b.y; vals[15] = (double)az * b.z;
    wave_reduce16_store(vals, bpart + blockIdx.x * 16);
}

// ---------------------------------------------------------------------------
// Partial sums for the final fit (a = p1, b = temppc). grid BPGRID x 64.
__global__ void fit_partial(const float* __restrict__ a, const float* __restrict__ b,
                            double* __restrict__ bpart) {
    int q = blockIdx.x * 64 + threadIdx.x;
    float ax = a[3*q], ay = a[3*q+1], az = a[3*q+2];
    float bx = b[3*q], by = b[3*q+1], bz = b[3*q+2];
    double vals[16];
    vals[0] = 0.0;
    vals[1] = (double)ax;  vals[2] = (double)ay;  vals[3] = (double)az;
    vals[4] = (double)bx;  vals[5] = (double)by;  vals[6] = (double)bz;
    vals[7]  = (double)ax * bx; vals[8]  = (double)ax * by; vals[9]  = (double)ax * bz;
    vals[10] = (double)ay * bx; vals[11] = (double)ay * by; vals[12] = (double)ay * bz;
    vals[13] = (double)az * bx; vals[14] = (double)az * by; vals[15] = (double)az * bz;
    wave_reduce16_store(vals, bpart + blockIdx.x * 16);
}

// ---------------------------------------------------------------------------
// Kabsch via Jacobi eigendecomposition of H^T H (double, single thread).
__device__ void kabsch3(const double H[3][3], const double c1[3], const double c2[3],
                        double R[3][3], double t[3]) {
    double A[3][3];
    for (int i = 0; i < 3; ++i)
        for (int j = 0; j < 3; ++j) {
            double sacc = 0.0;
            for (int k = 0; k < 3; ++k) sacc += H[k][i] * H[k][j];
            A[i][j] = sacc;
        }
    double V[3][3] = {{1,0,0},{0,1,0},{0,0,1}};
    for (int sweep = 0; sweep < 8; ++sweep) {
        const int PQ[3][2] = {{0,1},{0,2},{1,2}};
        for (int m = 0; m < 3; ++m) {
            int p = PQ[m][0], q = PQ[m][1];
            double apq = A[p][q];
            if (fabs(apq) < 1e-300) continue;
            double app = A[p][p], aqq = A[q][q];
            double tau = (aqq - app) / (2.0 * apq);
            double tt = (tau >= 0.0) ? 1.0 / (tau + sqrt(1.0 + tau*tau))
                                     : 1.0 / (tau - sqrt(1.0 + tau*tau));
            double c = 1.0 / sqrt(1.0 + tt*tt), s = tt * c;
            A[p][p] = app - tt * apq;
            A[q][q] = aqq + tt * apq;
            A[p][q] = 0.0; A[q][p] = 0.0;
            int k = 3 - p - q;
            double akp = A[k][p], akq = A[k][q];
            A[k][p] = c*akp - s*akq; A[p][k] = A[k][p];
            A[k][q] = s*akp + c*akq; A[q][k] = A[k][q];
            for (int r = 0; r < 3; ++r) {
                double vp = V[r][p], vq = V[r][q];
                V[r][p] = c*vp - s*vq;
                V[r][q] = s*vp + c*vq;
            }
        }
    }
    double lam[3] = {A[0][0], A[1][1], A[2][2]};
    int ord[3] = {0,1,2};
    for (int i = 0; i < 2; ++i)
        for (int j = i+1; j < 3; ++j)
            if (lam[ord[j]] > lam[ord[i]]) { int tmp = ord[i]; ord[i] = ord[j]; ord[j] = tmp; }
    double v0[3] = {V[0][ord[0]], V[1][ord[0]], V[2][ord[0]]};
    double v1[3] = {V[0][ord[1]], V[1][ord[1]], V[2][ord[1]]};
    double v2[3] = {V[0][ord[2]], V[1][ord[2]], V[2][ord[2]]};

    double u0[3], u1[3], hv2[3];
    for (int i = 0; i < 3; ++i) u0[i] = H[i][0]*v0[0] + H[i][1]*v0[1] + H[i][2]*v0[2];
    double n0 = sqrt(u0[0]*u0[0] + u0[1]*u0[1] + u0[2]*u0[2]);
    n0 = fmax(n0, 1e-300);
    for (int i = 0; i < 3; ++i) u0[i] /= n0;

    for (int i = 0; i < 3; ++i) u1[i] = H[i][0]*v1[0] + H[i][1]*v1[1] + H[i][2]*v1[2];
    double d01 = u1[0]*u0[0] + u1[1]*u0[1] + u1[2]*u0[2];
    for (int i = 0; i < 3; ++i) u1[i] -= d01 * u0[i];
    double n1 = sqrt(u1[0]*u1[0] + u1[1]*u1[1] + u1[2]*u1[2]);
    n1 = fmax(n1, 1e-300);
    for (int i = 0; i < 3; ++i) u1[i] /= n1;

    double u2[3] = {u0[1]*u1[2] - u0[2]*u1[1],
                    u0[2]*u1[0] - u0[0]*u1[2],
                    u0[0]*u1[1] - u0[1]*u1[0]};
    for (int i = 0; i < 3; ++i) hv2[i] = H[i][0]*v2[0] + H[i][1]*v2[1] + H[i][2]*v2[2];
    if (hv2[0]*u2[0] + hv2[1]*u2[1] + hv2[2]*u2[2] < 0.0) {
        v2[0] = -v2[0]; v2[1] = -v2[1]; v2[2] = -v2[2];
    }
    double cx = v1[1]*v2[2] - v1[2]*v2[1];
    double cy = v1[2]*v2[0] - v1[0]*v2[2];
    double cz = v1[0]*v2[1] - v1[1]*v2[0];
    double detV = v0[0]*cx + v0[1]*cy + v0[2]*cz;
    double dsg = (detV < 0.0) ? -1.0 : 1.0;

    for (int i = 0; i < 3; ++i)
        for (int j = 0; j < 3; ++j)
            R[i][j] = v0[i]*u0[j] + v1[i]*u1[j] + dsg * v2[i]*u2[j];
    for (int i = 0; i < 3; ++i)
        t[i] = c2[i] - (R[i][0]*c1[0] + R[i][1]*c1[1] + R[i][2]*c1[2]);
}

__device__ __forceinline__ void sum_bpart(const double* __restrict__ bpart, double s[16]) {
    for (int k = 0; k < 16; ++k) s[k] = 0.0;
    for (int b = 0; b < BPGRID; ++b)
        for (int k = 0; k < 16; ++k) s[k] += bpart[b*16 + k];
}

__device__ __forceinline__ void build_H(const double s[16], double c1[3], double c2[3],
                                        double H[3][3]) {
    const double Nn = (double)N_PTS;
    c1[0] = s[1]/Nn; c1[1] = s[2]/Nn; c1[2] = s[3]/Nn;
    c2[0] = s[4]/Nn; c2[1] = s[5]/Nn; c2[2] = s[6]/Nn;
    for (int i = 0; i < 3; ++i)
        for (int j = 0; j < 3; ++j)
            H[i][j] = s[7 + 3*i + j] - Nn * c1[i] * c2[j];
}

// ---------------------------------------------------------------------------
// Fused update + transform. grid 32 x 256. Every block redundantly computes
// the (identical, deterministic) Kabsch fit; block 0 advances err/done history.
__global__ void update_transform(const double* __restrict__ bpart,
                                 float* __restrict__ temppc,
                                 double* __restrict__ err_hist,
                                 int* __restrict__ done_hist, int it) {
    __shared__ float sRt[12];
    __shared__ int   snd;
    if (done_hist[it]) {
        if (blockIdx.x == 0 && threadIdx.x == 0) {
            err_hist[it+1]  = err_hist[it];
            done_hist[it+1] = 1;
        }
        return;
    }
    if (threadIdx.x == 0) {
        double s[16];
        sum_bpart(bpart, s);
        double errnew = s[0] / (double)N_PTS;
        double err = err_hist[it];
        double rel = fabs((errnew - err) / err);   // nan on first iter -> false
        int nd = (rel < TOLV) ? 1 : 0;
        if (blockIdx.x == 0) {
            err_hist[it+1]  = nd ? err : errnew;
            done_hist[it+1] = nd;
        }
        snd = nd;
        if (!nd) {
            double c1[3], c2[3], H[3][3], R[3][3], t[3];
            build_H(s, c1, c2, H);
            kabsch3(H, c1, c2, R, t);
            for (int i = 0; i < 3; ++i) {
                sRt[3*i]   = (float)R[i][0];
                sRt[3*i+1] = (float)R[i][1];
                sRt[3*i+2] = (float)R[i][2];
                sRt[9+i]   = (float)t[i];
            }
        }
    }
    __syncthreads();
    if (snd) return;
    int i = blockIdx.x * 256 + threadIdx.x;
    float x = temppc[3*i], y = temppc[3*i+1], z = temppc[3*i+2];
    float nx = fmaf(sRt[0], x, fmaf(sRt[1], y, fmaf(sRt[2], z, sRt[9])));
    float ny = fmaf(sRt[3], x, fmaf(sRt[4], y, fmaf(sRt[5], z, sRt[10])));
    float nz = fmaf(sRt[6], x, fmaf(sRt[7], y, fmaf(sRt[8], z, sRt[11])));
    temppc[3*i]   = nx;
    temppc[3*i+1] = ny;
    temppc[3*i+2] = nz;
}

// ---------------------------------------------------------------------------
__global__ void final_svd(const double* __restrict__ bpart, float* __restrict__ out) {
    if (threadIdx.x != 0 || blockIdx.x != 0) return;
    double s[16];
    sum_bpart(bpart, s);
    double c1[3], c2[3], H[3][3], R[3][3], t[3];
    build_H(s, c1, c2, H);
    kabsch3(H, c1, c2, R, t);
    for (int i = 0; i < 3; ++i) {
        out[4*i + 0] = (float)R[i][0];
        out[4*i + 1] = (float)R[i][1];
        out[4*i + 2] = (float)R[i][2];
        out[4*i + 3] = (float)t[i];
    }
}

// ---------------------------------------------------------------------------
extern "C" void kernel_launch(void* const* d_in, const int* in_sizes, int n_in,
                              void* d_out, int out_size, void* d_ws, size_t ws_size,
                              hipStream_t stream) {
    const float* p1 = (const float*)d_in[0];
    const float* p2 = (const float*)d_in[1];
    float* out = (float*)d_out;
    char* ws = (char*)d_ws;

    float*          temppc    = (float*)         (ws + WS_TEMPPC);
    float4*         p2f       = (float4*)        (ws + WS_P2F);
    unsigned short* pidx      = (unsigned short*)(ws + WS_PIDX);
    double*         bpart     = (double*)        (ws + WS_BPART);
    double*         err_hist  = (double*)        (ws + WS_ERRH);
    int*            done_hist = (int*)           (ws + WS_DONEH);

    icp_init<<<32, 256, 0, stream>>>(p1, p2, temppc, p2f, err_hist, done_hist);
    for (int it = 0; it < STEPS; ++it) {
        nn_partial<<<dim3(8, NCH), 256, 0, stream>>>(temppc, p2f, pidx, done_hist, it);
        nn_combine<<<BPGRID, 64, 0, stream>>>(temppc, p2f, pidx, bpart, done_hist, it);
        update_transform<<<32, 256, 0, stream>>>(bpart, temppc, err_hist, done_hist, it);
    }
    fit_partial<<<BPGRID, 64, 0, stream>>>(p1, temppc, bpart);
    final_svd<<<1, 64, 0, stream>>>(bpart, out);
}